// Round 7
// baseline (472.231 us; speedup 1.0000x reference)
//
#include <hip/hip_runtime.h>

#define SEQ 2048
#define NB 4
#define DIN 768
#define EDIM 768
#define NH 12
#define QKVN 2304
#define QKW 1536
#define SCALE 0.125f
#define PADV -1e9f
#define INV12 (0.0833333333f)
#define PSW 520   // Ps row stride in elems
#define TQR 8     // q rows per block

typedef unsigned short ushort_t;
typedef __attribute__((ext_vector_type(8))) short bf16x8;
typedef __attribute__((ext_vector_type(4))) float f32x4;

__device__ __forceinline__ float bf2f(ushort_t u) {
    union { unsigned int i; float f; } v; v.i = ((unsigned int)u) << 16; return v.f;
}
__device__ __forceinline__ ushort_t f2bf(float f) {
    union { float f; unsigned int i; } v; v.f = f;
    unsigned int r = (v.i + 0x7fffu + ((v.i >> 16) & 1u)) >> 16;
    return (ushort_t)r;
}
__device__ __forceinline__ void gl_lds16(const ushort_t* g, ushort_t* l) {
    __builtin_amdgcn_global_load_lds(
        (const __attribute__((address_space(1))) unsigned int*)(g),
        (__attribute__((address_space(3))) unsigned int*)(l),
        16, 0, 0);
}

// ---------------- per-batch window size ----------------
__global__ void wsz_kernel(const int* __restrict__ mask, int* __restrict__ wszp) {
    int b = blockIdx.x;
    __shared__ int cnt;
    if (threadIdx.x == 0) cnt = 0;
    __syncthreads();
    int local = 0;
    for (int s = threadIdx.x; s < SEQ; s += blockDim.x)
        local += (mask[b * SEQ + s] == 0) ? 1 : 0;
    for (int o = 32; o; o >>= 1) local += __shfl_down(local, o, 64);
    if ((threadIdx.x & 63) == 0) atomicAdd(&cnt, local);
    __syncthreads();
    if (threadIdx.x == 0) {
        int len = cnt; if (len > 2048) len = 2048;
        float w = ceilf(((float)len * 10.0f) / 100.0f);
        int wsz = (int)w;
        if (wsz < 2) wsz = 2;
        wszp[b] = wsz;
    }
}

// ---------------- fp32 -> bf16 conversion, 3 regions in one launch ----------------
__global__ void cvt3_kernel(const float* __restrict__ s0, int n0,
                            const float* __restrict__ s1, int n1,
                            const float* __restrict__ s2, int n2,
                            ushort_t* __restrict__ d0, ushort_t* __restrict__ d1,
                            ushort_t* __restrict__ d2) {
    int i = blockIdx.x * blockDim.x + threadIdx.x;
    const float* src; ushort_t* dst; int off;
    if (i < n0)               { src = s0; dst = d0; off = i; }
    else if (i < n0 + n1)     { src = s1; dst = d1; off = i - n0; }
    else if (i < n0 + n1 + n2){ src = s2; dst = d2; off = i - n0 - n1; }
    else return;
    float4 f = ((const float4*)src)[off];
    ushort4 u;
    u.x = f2bf(f.x); u.y = f2bf(f.y); u.z = f2bf(f.z); u.w = f2bf(f.w);
    ((ushort4*)dst)[off] = u;
}

// ---------------- mmask nonzero-tile flags ----------------
__global__ void flag_kernel(const float* __restrict__ mmask, const int* __restrict__ wszp,
                            int* __restrict__ flags) {
    const int b = blockIdx.z, i16 = blockIdx.y;
    const int wsz = wszp[b];
    const int i0 = i16 * 16;
    const int jt0 = max(0, i0 - wsz) >> 6;
    const int jt1 = min(SEQ - 1, i0 + 15 + wsz) >> 6;
    const int jt = jt0 + blockIdx.x;
    if (jt > jt1) return;
    int any = 0;
    for (int e = threadIdx.x; e < 1024; e += 256) {
        int row = e >> 6, col = e & 63;
        float v = mmask[((size_t)b * SEQ + i0 + row) * SEQ + jt * 64 + col];
        any |= (v != 0.f);
    }
    if (any) flags[(b * 128 + i16) * 32 + jt] = 1;
}

// ---------------- 128x128 bf16 MFMA GEMM ----------------
template<int MODE>
__global__ __launch_bounds__(256) void mfma_gemm128(
    const ushort_t* __restrict__ A, const ushort_t* __restrict__ Bw,
    const float* __restrict__ bias, float* __restrict__ outf,
    ushort_t* __restrict__ qk, ushort_t* __restrict__ vt, int N, int K)
{
    __shared__ __align__(16) ushort_t Al[128 * 64];
    __shared__ __align__(16) ushort_t Bl[128 * 64];
    const int tid  = threadIdx.x;
    const int w    = tid >> 6;
    const int l    = tid & 63;
    const int quad = l >> 4;
    const int lr   = l & 15;
    const int mw   = (w >> 1) * 64;
    const int nw   = (w & 1) * 64;
    const int bm   = blockIdx.y * 128;
    const int bn   = blockIdx.x * 128;
    const int srow = l >> 3;
    const int sg   = (l & 7) ^ srow;

    f32x4 acc[4][4];
    #pragma unroll
    for (int i = 0; i < 4; ++i)
        #pragma unroll
        for (int j = 0; j < 4; ++j)
            #pragma unroll
            for (int r = 0; r < 4; ++r) acc[i][j][r] = 0.f;

    const ushort_t* ga = A  + (size_t)(bm + w * 32 + srow) * K + sg * 8;
    const ushort_t* gb = Bw + (size_t)(bn + w * 32 + srow) * K + sg * 8;
    ushort_t* la = &Al[(w * 32) * 64];
    ushort_t* lb = &Bl[(w * 32) * 64];

    for (int k0 = 0; k0 < K; k0 += 64) {
        __syncthreads();
        #pragma unroll
        for (int i = 0; i < 4; ++i)
            gl_lds16(ga + (size_t)(i * 8) * K + k0, la + i * 8 * 64);
        #pragma unroll
        for (int i = 0; i < 4; ++i)
            gl_lds16(gb + (size_t)(i * 8) * K + k0, lb + i * 8 * 64);
        __syncthreads();
        #pragma unroll
        for (int s = 0; s < 2; ++s) {
            bf16x8 af[4], bf[4];
            #pragma unroll
            for (int t = 0; t < 4; ++t)
                af[t] = *(const bf16x8*)&Al[(mw + t * 16 + lr) * 64 + (((4 * s + quad) ^ (lr & 7)) * 8)];
            #pragma unroll
            for (int t = 0; t < 4; ++t)
                bf[t] = *(const bf16x8*)&Bl[(nw + t * 16 + lr) * 64 + (((4 * s + quad) ^ (lr & 7)) * 8)];
            #pragma unroll
            for (int mt = 0; mt < 4; ++mt)
                #pragma unroll
                for (int nt = 0; nt < 4; ++nt)
                    acc[mt][nt] = __builtin_amdgcn_mfma_f32_16x16x32_bf16(af[mt], bf[nt], acc[mt][nt], 0, 0, 0);
        }
    }

    #pragma unroll
    for (int nt = 0; nt < 4; ++nt) {
        const int gn = bn + nw + nt * 16 + lr;
        const float bv = bias[gn];
        const int hh  = gn / 192;
        const int rem = gn - hh * 192;
        #pragma unroll
        for (int mt = 0; mt < 4; ++mt) {
            const int gm0 = bm + mw + mt * 16 + quad * 4;
            if (MODE == 0) {
                #pragma unroll
                for (int r = 0; r < 4; ++r)
                    outf[(size_t)(gm0 + r) * N + gn] = acc[mt][nt][r] + bv;
            } else if (rem < 128) {
                #pragma unroll
                for (int r = 0; r < 4; ++r)
                    qk[(size_t)(gm0 + r) * QKW + hh * 128 + rem] = f2bf(acc[mt][nt][r] + bv);
            } else {
                const int bb  = gm0 >> 11;
                const int tok = gm0 & (SEQ - 1);
                ushort4 st;
                st.x = f2bf(acc[mt][nt][0] + bv);
                st.y = f2bf(acc[mt][nt][1] + bv);
                st.z = f2bf(acc[mt][nt][2] + bv);
                st.w = f2bf(acc[mt][nt][3] + bv);
                *(ushort4*)&vt[((size_t)(bb * NH + hh) * 64 + (rem - 128)) * SEQ + tok] = st;
            }
        }
    }
}

// ---------------- fused windowed attention v5: 8-row q-tiles, grid 1024 ----------------
// 512 thr = 8 waves; waves 0-3 -> even head, 4-7 -> odd head. MFMA M-dim rows 8-15
// duplicate rows 0-7 (lr&7) and are ignored on output.
__global__ __launch_bounds__(512) void attn_kernel(
    const ushort_t* __restrict__ qk,    // [NB*SEQ][1536] bf16 (Q|K per head)
    const ushort_t* __restrict__ vt,    // [NB*NH*64][SEQ] bf16 (V transposed)
    const float* __restrict__ mmask,    // [NB][SEQ][SEQ]
    const int* __restrict__ wszp,       // [NB]
    const int* __restrict__ flags,      // [NB][128][32]
    ushort_t* __restrict__ values,      // [NB*SEQ][768] bf16
    float* __restrict__ attn_out)       // [NB][SEQ][SEQ]
{
    __shared__ __align__(16) ushort_t Ps[2][TQR * PSW];  // 16.6 KB
    __shared__ float lsump[2][4][TQR];
    const int tid  = threadIdx.x;
    const int w    = tid >> 6;       // 0..7
    const int hg   = w >> 2;         // head-group 0/1
    const int ww   = w & 3;          // wave within head
    const int lane = tid & 63;
    const int quad = lane >> 4;
    const int lr   = lane & 15;

    const int lin  = blockIdx.x;
    const int s    = lin & 1;
    const int b    = (lin >> 1) & 3;
    const int i8   = (lin >> 3) + 128 * s;   // 0..255
    const int iq0  = i8 * TQR;

    const int wsz  = wszp[b];
    const int jlo  = max(0, iq0 - wsz);
    const int jhi  = min(SEQ - 1, iq0 + TQR - 1 + wsz);
    const int jt0  = jlo >> 6;
    const int nch  = (jhi >> 6) - jt0 + 1;   // <= 8
    const int jbase = jt0 << 6;
    const int span  = nch << 6;              // <= 512
    const int fbase = (b * 128 + (i8 >> 1)) * 32;

    // mean-accum ownership: row = tid&7, col-group = tid>>3 (8 cols each, 64 groups)
    const int arow = tid & 7;
    const int acg  = tid >> 3;
    float acc[8];
    #pragma unroll
    for (int k = 0; k < 8; ++k) acc[k] = 0.f;

    const ushort_t* kbase = qk + (size_t)b * SEQ * QKW + 64;
    const ushort_t* vhead = vt + (size_t)b * NH * 64 * SEQ;
    const int qrow = iq0 + (lr & 7);         // A rows 8-15 duplicate 0-7

    for (int hp = 0; hp < NH / 2; ++hp) {
        const int h  = hp * 2 + hg;
        const int hq = h * 128;
        const ushort_t* qbase = qk + (size_t)(b * SEQ + qrow) * QKW + hq;
        const bf16x8 qf0 = *(const bf16x8*)(qbase + quad * 8);
        const bf16x8 qf1 = *(const bf16x8*)(qbase + 32 + quad * 8);

        // ---- QK + exp for this wave's chunks (ci = ww, ww+4) ----
        float ls[4] = {0.f, 0.f, 0.f, 0.f};
        #pragma unroll
        for (int cc = 0; cc < 2; ++cc) {
            const int ci = ww + cc * 4;
            if (ci < nch) {
                const int jc = jbase + ci * 64;
                f32x4 s4[4];
                #pragma unroll
                for (int t = 0; t < 4; ++t) {
                    const ushort_t* kr = kbase + (size_t)(jc + t * 16 + lr) * QKW + hq;
                    bf16x8 kf0 = *(const bf16x8*)(kr + quad * 8);
                    bf16x8 kf1 = *(const bf16x8*)(kr + 32 + quad * 8);
                    #pragma unroll
                    for (int r = 0; r < 4; ++r) s4[t][r] = 0.f;
                    s4[t] = __builtin_amdgcn_mfma_f32_16x16x32_bf16(qf0, kf0, s4[t], 0, 0, 0);
                    s4[t] = __builtin_amdgcn_mfma_f32_16x16x32_bf16(qf1, kf1, s4[t], 0, 0, 0);
                }
                const int anym = flags[fbase + jt0 + ci];
                #pragma unroll
                for (int t = 0; t < 4; ++t) {
                    const int gj = jc + t * 16 + lr;
                    #pragma unroll
                    for (int r = 0; r < 4; ++r) {
                        const int rloc = quad * 4 + r;          // 0..15; 8-15 dup of 0-7
                        const int gi = iq0 + (rloc & 7);
                        float mm = 0.f;
                        if (anym) mm = mmask[((size_t)b * SEQ + gi) * SEQ + gj];
                        const int dist = gi > gj ? gi - gj : gj - gi;
                        const float p = (dist > wsz) ? 0.f : __expf(fmaf(s4[t][r], SCALE, mm));
                        ls[r] += p;
                        if (rloc < TQR)
                            Ps[hg][rloc * PSW + (ci * 64 + t * 16 + lr)] = f2bf(p);
                    }
                }
            }
        }
        #pragma unroll
        for (int r = 0; r < 4; ++r) {
            #pragma unroll
            for (int m = 8; m; m >>= 1) ls[r] += __shfl_xor(ls[r], m, 16);
        }
        if (lr == 0 && quad < 2) {
            #pragma unroll
            for (int r = 0; r < 4; ++r) lsump[hg][ww][quad * 4 + r] = ls[r];
        }
        __syncthreads();

        // ---- head-mean accumulation into registers (both heads of the pair) ----
        if (acg * 8 < span) {
            const float l0 = lsump[0][0][arow] + lsump[0][1][arow] + lsump[0][2][arow] + lsump[0][3][arow];
            const float l1 = lsump[1][0][arow] + lsump[1][1][arow] + lsump[1][2][arow] + lsump[1][3][arow];
            const float sc0 = INV12 / l0;
            const float sc1 = INV12 / l1;
            const ushort_t* p0 = &Ps[0][arow * PSW + acg * 8];
            const ushort_t* p1 = &Ps[1][arow * PSW + acg * 8];
            #pragma unroll
            for (int k = 0; k < 2; ++k) {
                ushort4 u0 = *(const ushort4*)(p0 + k * 4);
                ushort4 u1 = *(const ushort4*)(p1 + k * 4);
                acc[k * 4 + 0] = fmaf(bf2f(u0.x), sc0, fmaf(bf2f(u1.x), sc1, acc[k * 4 + 0]));
                acc[k * 4 + 1] = fmaf(bf2f(u0.y), sc0, fmaf(bf2f(u1.y), sc1, acc[k * 4 + 1]));
                acc[k * 4 + 2] = fmaf(bf2f(u0.z), sc0, fmaf(bf2f(u1.z), sc1, acc[k * 4 + 2]));
                acc[k * 4 + 3] = fmaf(bf2f(u0.w), sc0, fmaf(bf2f(u1.w), sc1, acc[k * 4 + 3]));
            }
        }

        // ---- PV: wave computes head h, d-slice [ww*16, ww*16+16) ----
        {
            f32x4 oacc;
            #pragma unroll
            for (int r = 0; r < 4; ++r) oacc[r] = 0.f;
            const ushort_t* vrow = vhead + (size_t)(h * 64 + ww * 16 + lr) * SEQ + jbase;
            const ushort_t* prow = &Ps[hg][(lr & 7) * PSW];   // P rows 8-15 dup 0-7
            for (int ci = 0; ci < nch; ++ci) {
                const int tok0 = ci * 64;
                #pragma unroll
                for (int s2 = 0; s2 < 2; ++s2) {
                    bf16x8 pa = *(const bf16x8*)(prow + tok0 + s2 * 32 + quad * 8);
                    bf16x8 vf = *(const bf16x8*)(vrow + tok0 + s2 * 32 + quad * 8);
                    oacc = __builtin_amdgcn_mfma_f32_16x16x32_bf16(pa, vf, oacc, 0, 0, 0);
                }
            }
            if (quad < 2) {
                float lr4[4];
                #pragma unroll
                for (int r = 0; r < 4; ++r)
                    lr4[r] = lsump[hg][0][quad * 4 + r] + lsump[hg][1][quad * 4 + r] +
                             lsump[hg][2][quad * 4 + r] + lsump[hg][3][quad * 4 + r];
                #pragma unroll
                for (int r = 0; r < 4; ++r) {
                    const int row = iq0 + quad * 4 + r;
                    values[(size_t)(b * SEQ + row) * EDIM + h * 64 + ww * 16 + lr] =
                        f2bf(oacc[r] / lr4[r]);
                }
            }
        }
        __syncthreads();   // Ps/lsump reuse next head pair
    }

    // ---- write attn_mean ----
    if (acg * 8 < span) {
        float* dst = attn_out + ((size_t)b * SEQ + iq0 + arow) * SEQ + jbase + acg * 8;
        #pragma unroll
        for (int k = 0; k < 2; ++k) {
            float4 v = { acc[k * 4 + 0], acc[k * 4 + 1], acc[k * 4 + 2], acc[k * 4 + 3] };
            *(float4*)(dst + k * 4) = v;
        }
    }
    {
        const int c4lo = jbase >> 2;
        const int c4hi = (jbase + span) >> 2;
        const float4 z = {0.f, 0.f, 0.f, 0.f};
        for (int f = tid; f < TQR * 512; f += 512) {
            const int i  = f >> 9;
            const int c4 = f & 511;
            if (c4 < c4lo || c4 >= c4hi)
                *(float4*)(attn_out + ((size_t)b * SEQ + iq0 + i) * SEQ + c4 * 4) = z;
        }
    }
}

extern "C" void kernel_launch(void* const* d_in, const int* in_sizes, int n_in,
                              void* d_out, int out_size, void* d_ws, size_t ws_size,
                              hipStream_t stream) {
    const float* x      = (const float*)d_in[0];
    const int*   pad    = (const int*)d_in[1];
    const float* mmask  = (const float*)d_in[2];
    const float* qkv_w  = (const float*)d_in[3];
    const float* qkv_b  = (const float*)d_in[4];
    const float* o_w    = (const float*)d_in[5];
    const float* o_b    = (const float*)d_in[6];

    float* out_o    = (float*)d_out;
    float* out_attn = out_o + (size_t)NB * SEQ * EDIM;

    ushort_t* qk     = (ushort_t*)d_ws;                       // NB*SEQ*1536
    ushort_t* vt     = qk + (size_t)NB * SEQ * QKW;           // NB*NH*64*SEQ
    ushort_t* xb     = vt + (size_t)NB * NH * 64 * SEQ;       // x bf16
    ushort_t* values = xb;                                    // alias (after GEMM1)
    ushort_t* wqkvb  = xb + (size_t)NB * SEQ * DIN;
    ushort_t* wob    = wqkvb + (size_t)QKVN * DIN;
    int*      wszp   = (int*)(wob + (size_t)EDIM * EDIM);
    int*      flags  = wszp + 4;

    hipMemsetAsync(flags, 0, (size_t)NB * 128 * 32 * sizeof(int), stream);

    wsz_kernel<<<NB, 256, 0, stream>>>(pad, wszp);
    flag_kernel<<<dim3(8, 128, NB), 256, 0, stream>>>(mmask, wszp, flags);

    const int nx = NB * SEQ * DIN / 4, nw1 = QKVN * DIN / 4, nw2 = EDIM * EDIM / 4;
    cvt3_kernel<<<(nx + nw1 + nw2 + 255) / 256, 256, 0, stream>>>(
        x, nx, qkv_w, nw1, o_w, nw2, xb, wqkvb, wob);

    mfma_gemm128<1><<<dim3(QKVN / 128, (NB * SEQ) / 128), 256, 0, stream>>>(
        xb, wqkvb, qkv_b, nullptr, qk, vt, QKVN, DIN);

    attn_kernel<<<1024, 512, 0, stream>>>(
        qk, vt, mmask, wszp, flags, values, out_attn);

    mfma_gemm128<0><<<dim3(EDIM / 128, (NB * SEQ) / 128), 256, 0, stream>>>(
        values, wob, o_b, out_o, nullptr, nullptr, EDIM, EDIM);
}

// Round 8
// 344.350 us; speedup vs baseline: 1.3714x; 1.3714x over previous
//
#include <hip/hip_runtime.h>

#define SEQ 2048
#define NB 4
#define DIN 768
#define EDIM 768
#define NH 12
#define QKVN 2304
#define QKW 1536
#define SCALE 0.125f
#define PADV -1e9f
#define INV12 (0.0833333333f)
#define PSW 520   // Ps row stride in elems (bank de-conflict: 520*2/4 % 32 == 4)

typedef unsigned short ushort_t;
typedef __attribute__((ext_vector_type(8))) short bf16x8;
typedef __attribute__((ext_vector_type(4))) float f32x4;

__device__ __forceinline__ float bf2f(ushort_t u) {
    union { unsigned int i; float f; } v; v.i = ((unsigned int)u) << 16; return v.f;
}
__device__ __forceinline__ ushort_t f2bf(float f) {
    union { float f; unsigned int i; } v; v.f = f;
    unsigned int r = (v.i + 0x7fffu + ((v.i >> 16) & 1u)) >> 16;
    return (ushort_t)r;
}
__device__ __forceinline__ void gl_lds16(const ushort_t* g, ushort_t* l) {
    __builtin_amdgcn_global_load_lds(
        (const __attribute__((address_space(1))) unsigned int*)(g),
        (__attribute__((address_space(3))) unsigned int*)(l),
        16, 0, 0);
}

// ---------------- per-batch window size ----------------
__global__ void wsz_kernel(const int* __restrict__ mask, int* __restrict__ wszp) {
    int b = blockIdx.x;
    __shared__ int cnt;
    if (threadIdx.x == 0) cnt = 0;
    __syncthreads();
    int local = 0;
    for (int s = threadIdx.x; s < SEQ; s += blockDim.x)
        local += (mask[b * SEQ + s] == 0) ? 1 : 0;
    for (int o = 32; o; o >>= 1) local += __shfl_down(local, o, 64);
    if ((threadIdx.x & 63) == 0) atomicAdd(&cnt, local);
    __syncthreads();
    if (threadIdx.x == 0) {
        int len = cnt; if (len > 2048) len = 2048;
        float w = ceilf(((float)len * 10.0f) / 100.0f);
        int wsz = (int)w;
        if (wsz < 2) wsz = 2;
        wszp[b] = wsz;
    }
}

// ---------------- fp32 -> bf16 conversion, 3 regions in one launch ----------------
__global__ void cvt3_kernel(const float* __restrict__ s0, int n0,
                            const float* __restrict__ s1, int n1,
                            const float* __restrict__ s2, int n2,
                            ushort_t* __restrict__ d0, ushort_t* __restrict__ d1,
                            ushort_t* __restrict__ d2) {
    int i = blockIdx.x * blockDim.x + threadIdx.x;
    const float* src; ushort_t* dst; int off;
    if (i < n0)               { src = s0; dst = d0; off = i; }
    else if (i < n0 + n1)     { src = s1; dst = d1; off = i - n0; }
    else if (i < n0 + n1 + n2){ src = s2; dst = d2; off = i - n0 - n1; }
    else return;
    float4 f = ((const float4*)src)[off];
    ushort4 u;
    u.x = f2bf(f.x); u.y = f2bf(f.y); u.z = f2bf(f.z); u.w = f2bf(f.w);
    ((ushort4*)dst)[off] = u;
}

// ---------------- mmask nonzero-tile flags ----------------
__global__ void flag_kernel(const float* __restrict__ mmask, const int* __restrict__ wszp,
                            int* __restrict__ flags) {
    const int b = blockIdx.z, i16 = blockIdx.y;
    const int wsz = wszp[b];
    const int i0 = i16 * 16;
    const int jt0 = max(0, i0 - wsz) >> 6;
    const int jt1 = min(SEQ - 1, i0 + 15 + wsz) >> 6;
    const int jt = jt0 + blockIdx.x;
    if (jt > jt1) return;
    int any = 0;
    for (int e = threadIdx.x; e < 1024; e += 256) {
        int row = e >> 6, col = e & 63;
        float v = mmask[((size_t)b * SEQ + i0 + row) * SEQ + jt * 64 + col];
        any |= (v != 0.f);
    }
    if (any) flags[(b * 128 + i16) * 32 + jt] = 1;
}

// ---------------- 128x128 bf16 MFMA GEMM ----------------
template<int MODE>
__global__ __launch_bounds__(256) void mfma_gemm128(
    const ushort_t* __restrict__ A, const ushort_t* __restrict__ Bw,
    const float* __restrict__ bias, float* __restrict__ outf,
    ushort_t* __restrict__ qk, ushort_t* __restrict__ vt, int N, int K)
{
    __shared__ __align__(16) ushort_t Al[128 * 64];
    __shared__ __align__(16) ushort_t Bl[128 * 64];
    const int tid  = threadIdx.x;
    const int w    = tid >> 6;
    const int l    = tid & 63;
    const int quad = l >> 4;
    const int lr   = l & 15;
    const int mw   = (w >> 1) * 64;
    const int nw   = (w & 1) * 64;
    const int bm   = blockIdx.y * 128;
    const int bn   = blockIdx.x * 128;
    const int srow = l >> 3;
    const int sg   = (l & 7) ^ srow;

    f32x4 acc[4][4];
    #pragma unroll
    for (int i = 0; i < 4; ++i)
        #pragma unroll
        for (int j = 0; j < 4; ++j)
            #pragma unroll
            for (int r = 0; r < 4; ++r) acc[i][j][r] = 0.f;

    const ushort_t* ga = A  + (size_t)(bm + w * 32 + srow) * K + sg * 8;
    const ushort_t* gb = Bw + (size_t)(bn + w * 32 + srow) * K + sg * 8;
    ushort_t* la = &Al[(w * 32) * 64];
    ushort_t* lb = &Bl[(w * 32) * 64];

    for (int k0 = 0; k0 < K; k0 += 64) {
        __syncthreads();
        #pragma unroll
        for (int i = 0; i < 4; ++i)
            gl_lds16(ga + (size_t)(i * 8) * K + k0, la + i * 8 * 64);
        #pragma unroll
        for (int i = 0; i < 4; ++i)
            gl_lds16(gb + (size_t)(i * 8) * K + k0, lb + i * 8 * 64);
        __syncthreads();
        #pragma unroll
        for (int s = 0; s < 2; ++s) {
            bf16x8 af[4], bf[4];
            #pragma unroll
            for (int t = 0; t < 4; ++t)
                af[t] = *(const bf16x8*)&Al[(mw + t * 16 + lr) * 64 + (((4 * s + quad) ^ (lr & 7)) * 8)];
            #pragma unroll
            for (int t = 0; t < 4; ++t)
                bf[t] = *(const bf16x8*)&Bl[(nw + t * 16 + lr) * 64 + (((4 * s + quad) ^ (lr & 7)) * 8)];
            #pragma unroll
            for (int mt = 0; mt < 4; ++mt)
                #pragma unroll
                for (int nt = 0; nt < 4; ++nt)
                    acc[mt][nt] = __builtin_amdgcn_mfma_f32_16x16x32_bf16(af[mt], bf[nt], acc[mt][nt], 0, 0, 0);
        }
    }

    #pragma unroll
    for (int nt = 0; nt < 4; ++nt) {
        const int gn = bn + nw + nt * 16 + lr;
        const float bv = bias[gn];
        const int hh  = gn / 192;
        const int rem = gn - hh * 192;
        #pragma unroll
        for (int mt = 0; mt < 4; ++mt) {
            const int gm0 = bm + mw + mt * 16 + quad * 4;
            if (MODE == 0) {
                #pragma unroll
                for (int r = 0; r < 4; ++r)
                    outf[(size_t)(gm0 + r) * N + gn] = acc[mt][nt][r] + bv;
            } else if (rem < 128) {
                #pragma unroll
                for (int r = 0; r < 4; ++r)
                    qk[(size_t)(gm0 + r) * QKW + hh * 128 + rem] = f2bf(acc[mt][nt][r] + bv);
            } else {
                const int bb  = gm0 >> 11;
                const int tok = gm0 & (SEQ - 1);
                ushort4 st;
                st.x = f2bf(acc[mt][nt][0] + bv);
                st.y = f2bf(acc[mt][nt][1] + bv);
                st.z = f2bf(acc[mt][nt][2] + bv);
                st.w = f2bf(acc[mt][nt][3] + bv);
                *(ushort4*)&vt[((size_t)(bb * NH + hh) * 64 + (rem - 128)) * SEQ + tok] = st;
            }
        }
    }
}

// ---------------- fused windowed attention v6: 768 thr, 3 heads concurrent ----------------
// Grid 512 (XCD-swizzled), 12 waves; waves 4g..4g+3 -> head hp*3+g. Per-head code
// identical to v4; triple-buffered Ps/lsump. 16 q-rows per block.
__global__ __launch_bounds__(768) void attn_kernel(
    const ushort_t* __restrict__ qk,    // [NB*SEQ][1536] bf16 (Q|K per head)
    const ushort_t* __restrict__ vt,    // [NB*NH*64][SEQ] bf16 (V transposed)
    const float* __restrict__ mmask,    // [NB][SEQ][SEQ]
    const int* __restrict__ wszp,       // [NB]
    const int* __restrict__ flags,      // [NB][128][32]
    ushort_t* __restrict__ values,      // [NB*SEQ][768] bf16
    float* __restrict__ attn_out)       // [NB][SEQ][SEQ]
{
    __shared__ __align__(16) ushort_t Ps[3][16 * PSW];  // 49.9 KB
    __shared__ float lsump[3][4][16];
    const int tid  = threadIdx.x;
    const int w    = tid >> 6;       // 0..11
    const int hg   = w >> 2;         // head-group 0/1/2
    const int ww   = w & 3;          // wave within head
    const int lane = tid & 63;
    const int quad = lane >> 4;
    const int lr   = lane & 15;

    const int lin  = blockIdx.x;
    const int s    = lin & 1;
    const int b    = (lin >> 1) & 3;
    const int i16  = (lin >> 3) + 64 * s;
    const int iq0  = i16 * 16;

    const int wsz  = wszp[b];
    const int jlo  = max(0, iq0 - wsz);
    const int jhi  = min(SEQ - 1, iq0 + 15 + wsz);
    const int jt0  = jlo >> 6;
    const int nch  = (jhi >> 6) - jt0 + 1;   // <= 8
    const int jbase = jt0 << 6;
    const int span  = nch << 6;              // <= 512
    const int fbase = (b * 128 + i16) * 32;

    // mean-accum ownership (first 512 threads): row = tid&15, col-group = tid>>4
    const int arow = tid & 15;
    const int acg  = tid >> 4;               // 0..47; only 0..31 own columns
    float acc[16];
    #pragma unroll
    for (int k = 0; k < 16; ++k) acc[k] = 0.f;

    const ushort_t* kbase = qk + (size_t)b * SEQ * QKW + 64;
    const ushort_t* vhead = vt + (size_t)b * NH * 64 * SEQ;

    for (int hp = 0; hp < NH / 3; ++hp) {
        const int h  = hp * 3 + hg;
        const int hq = h * 128;
        const ushort_t* qbase = qk + (size_t)(b * SEQ + iq0 + lr) * QKW + hq;
        const bf16x8 qf0 = *(const bf16x8*)(qbase + quad * 8);
        const bf16x8 qf1 = *(const bf16x8*)(qbase + 32 + quad * 8);

        // ---- QK + exp for this wave's chunks (ci = ww, ww+4) ----
        float ls[4] = {0.f, 0.f, 0.f, 0.f};
        #pragma unroll
        for (int cc = 0; cc < 2; ++cc) {
            const int ci = ww + cc * 4;
            if (ci < nch) {
                const int jc = jbase + ci * 64;
                f32x4 s4[4];
                #pragma unroll
                for (int t = 0; t < 4; ++t) {
                    const ushort_t* kr = kbase + (size_t)(jc + t * 16 + lr) * QKW + hq;
                    bf16x8 kf0 = *(const bf16x8*)(kr + quad * 8);
                    bf16x8 kf1 = *(const bf16x8*)(kr + 32 + quad * 8);
                    #pragma unroll
                    for (int r = 0; r < 4; ++r) s4[t][r] = 0.f;
                    s4[t] = __builtin_amdgcn_mfma_f32_16x16x32_bf16(qf0, kf0, s4[t], 0, 0, 0);
                    s4[t] = __builtin_amdgcn_mfma_f32_16x16x32_bf16(qf1, kf1, s4[t], 0, 0, 0);
                }
                const int anym = flags[fbase + jt0 + ci];
                #pragma unroll
                for (int t = 0; t < 4; ++t) {
                    const int gj = jc + t * 16 + lr;
                    #pragma unroll
                    for (int r = 0; r < 4; ++r) {
                        const int gi = iq0 + quad * 4 + r;
                        float mm = 0.f;
                        if (anym) mm = mmask[((size_t)b * SEQ + gi) * SEQ + gj];
                        const int dist = gi > gj ? gi - gj : gj - gi;
                        const float p = (dist > wsz) ? 0.f : __expf(fmaf(s4[t][r], SCALE, mm));
                        ls[r] += p;
                        Ps[hg][(quad * 4 + r) * PSW + (ci * 64 + t * 16 + lr)] = f2bf(p);
                    }
                }
            }
        }
        #pragma unroll
        for (int r = 0; r < 4; ++r) {
            #pragma unroll
            for (int m = 8; m; m >>= 1) ls[r] += __shfl_xor(ls[r], m, 16);
        }
        if (lr == 0) {
            #pragma unroll
            for (int r = 0; r < 4; ++r) lsump[hg][ww][quad * 4 + r] = ls[r];
        }
        __syncthreads();

        // ---- head-mean accumulation into registers (3 heads of the trio) ----
        if (acg < 32 && acg * 16 < span) {
            const float l0 = lsump[0][0][arow] + lsump[0][1][arow] + lsump[0][2][arow] + lsump[0][3][arow];
            const float l1 = lsump[1][0][arow] + lsump[1][1][arow] + lsump[1][2][arow] + lsump[1][3][arow];
            const float l2 = lsump[2][0][arow] + lsump[2][1][arow] + lsump[2][2][arow] + lsump[2][3][arow];
            const float sc0 = INV12 / l0;
            const float sc1 = INV12 / l1;
            const float sc2 = INV12 / l2;
            const ushort_t* p0 = &Ps[0][arow * PSW + acg * 16];
            const ushort_t* p1 = &Ps[1][arow * PSW + acg * 16];
            const ushort_t* p2 = &Ps[2][arow * PSW + acg * 16];
            #pragma unroll
            for (int k = 0; k < 4; ++k) {
                ushort4 u0 = *(const ushort4*)(p0 + k * 4);
                ushort4 u1 = *(const ushort4*)(p1 + k * 4);
                ushort4 u2 = *(const ushort4*)(p2 + k * 4);
                acc[k * 4 + 0] += bf2f(u0.x) * sc0 + bf2f(u1.x) * sc1 + bf2f(u2.x) * sc2;
                acc[k * 4 + 1] += bf2f(u0.y) * sc0 + bf2f(u1.y) * sc1 + bf2f(u2.y) * sc2;
                acc[k * 4 + 2] += bf2f(u0.z) * sc0 + bf2f(u1.z) * sc1 + bf2f(u2.z) * sc2;
                acc[k * 4 + 3] += bf2f(u0.w) * sc0 + bf2f(u1.w) * sc1 + bf2f(u2.w) * sc2;
            }
        }

        // ---- PV: wave computes head h, d-slice [ww*16, ww*16+16) ----
        {
            f32x4 oacc;
            #pragma unroll
            for (int r = 0; r < 4; ++r) oacc[r] = 0.f;
            const ushort_t* vrow = vhead + (size_t)(h * 64 + ww * 16 + lr) * SEQ + jbase;
            for (int ci = 0; ci < nch; ++ci) {
                const int tok0 = ci * 64;
                #pragma unroll
                for (int s2 = 0; s2 < 2; ++s2) {
                    bf16x8 pa = *(const bf16x8*)&Ps[hg][lr * PSW + tok0 + s2 * 32 + quad * 8];
                    bf16x8 vf = *(const bf16x8*)(vrow + tok0 + s2 * 32 + quad * 8);
                    oacc = __builtin_amdgcn_mfma_f32_16x16x32_bf16(pa, vf, oacc, 0, 0, 0);
                }
            }
            float lr4[4];
            #pragma unroll
            for (int r = 0; r < 4; ++r)
                lr4[r] = lsump[hg][0][quad * 4 + r] + lsump[hg][1][quad * 4 + r] +
                         lsump[hg][2][quad * 4 + r] + lsump[hg][3][quad * 4 + r];
            #pragma unroll
            for (int r = 0; r < 4; ++r) {
                const int row = iq0 + quad * 4 + r;
                values[(size_t)(b * SEQ + row) * EDIM + h * 64 + ww * 16 + lr] =
                    f2bf(oacc[r] / lr4[r]);
            }
        }
        __syncthreads();   // Ps/lsump reuse next head trio
    }

    // ---- write attn_mean ----
    if (acg < 32 && acg * 16 < span) {
        float* dst = attn_out + ((size_t)b * SEQ + iq0 + arow) * SEQ + jbase + acg * 16;
        #pragma unroll
        for (int k = 0; k < 4; ++k) {
            float4 v = { acc[k * 4 + 0], acc[k * 4 + 1], acc[k * 4 + 2], acc[k * 4 + 3] };
            *(float4*)(dst + k * 4) = v;
        }
    }
    {
        const int c4lo = jbase >> 2;
        const int c4hi = (jbase + span) >> 2;
        const float4 z = {0.f, 0.f, 0.f, 0.f};
        for (int f = tid; f < 16 * 512; f += 768) {
            const int i  = f >> 9;
            const int c4 = f & 511;
            if (c4 < c4lo || c4 >= c4hi)
                *(float4*)(attn_out + ((size_t)b * SEQ + iq0 + i) * SEQ + c4 * 4) = z;
        }
    }
}

extern "C" void kernel_launch(void* const* d_in, const int* in_sizes, int n_in,
                              void* d_out, int out_size, void* d_ws, size_t ws_size,
                              hipStream_t stream) {
    const float* x      = (const float*)d_in[0];
    const int*   pad    = (const int*)d_in[1];
    const float* mmask  = (const float*)d_in[2];
    const float* qkv_w  = (const float*)d_in[3];
    const float* qkv_b  = (const float*)d_in[4];
    const float* o_w    = (const float*)d_in[5];
    const float* o_b    = (const float*)d_in[6];

    float* out_o    = (float*)d_out;
    float* out_attn = out_o + (size_t)NB * SEQ * EDIM;

    ushort_t* qk     = (ushort_t*)d_ws;                       // NB*SEQ*1536
    ushort_t* vt     = qk + (size_t)NB * SEQ * QKW;           // NB*NH*64*SEQ
    ushort_t* xb     = vt + (size_t)NB * NH * 64 * SEQ;       // x bf16
    ushort_t* values = xb;                                    // alias (after GEMM1)
    ushort_t* wqkvb  = xb + (size_t)NB * SEQ * DIN;
    ushort_t* wob    = wqkvb + (size_t)QKVN * DIN;
    int*      wszp   = (int*)(wob + (size_t)EDIM * EDIM);
    int*      flags  = wszp + 4;

    hipMemsetAsync(flags, 0, (size_t)NB * 128 * 32 * sizeof(int), stream);

    wsz_kernel<<<NB, 256, 0, stream>>>(pad, wszp);
    flag_kernel<<<dim3(8, 128, NB), 256, 0, stream>>>(mmask, wszp, flags);

    const int nx = NB * SEQ * DIN / 4, nw1 = QKVN * DIN / 4, nw2 = EDIM * EDIM / 4;
    cvt3_kernel<<<(nx + nw1 + nw2 + 255) / 256, 256, 0, stream>>>(
        x, nx, qkv_w, nw1, o_w, nw2, xb, wqkvb, wob);

    mfma_gemm128<1><<<dim3(QKVN / 128, (NB * SEQ) / 128), 256, 0, stream>>>(
        xb, wqkvb, qkv_b, nullptr, qk, vt, QKVN, DIN);

    attn_kernel<<<512, 768, 0, stream>>>(
        qk, vt, mmask, wszp, flags, values, out_attn);

    mfma_gemm128<0><<<dim3(EDIM / 128, (NB * SEQ) / 128), 256, 0, stream>>>(
        values, wob, o_b, out_o, nullptr, nullptr, EDIM, EDIM);
}